// Round 7
// baseline (642.829 us; speedup 1.0000x reference)
//
#include <hip/hip_runtime.h>
#include <hip/hip_bf16.h>

#define IN_DIM 500
#define HID 128
#define OUTD 40
#define KPAD 512

typedef _Float16 f16x8 __attribute__((ext_vector_type(8)));
typedef float f32x16 __attribute__((ext_vector_type(16)));
typedef unsigned short u16x8 __attribute__((ext_vector_type(8)));
typedef unsigned short u16x4 __attribute__((ext_vector_type(4)));

static __device__ __forceinline__ float rsqrt_acc(float x) {
  float r = rsqrtf(x);
  return r * (1.5f - 0.5f * x * r * r);
}

// fp16 (10 mantissa bits): intermediates h1/hrelu/h2 and gemm1 operands
static __device__ __forceinline__ unsigned short h16_of(float f) {
  _Float16 h = (_Float16)f;
  return __builtin_bit_cast(unsigned short, h);
}
static __device__ __forceinline__ float h16_back(unsigned short u) {
  return (float)__builtin_bit_cast(_Float16, u);
}

// ---- zero-fill (graph-capture-safe) ----
__global__ void zero_kernel(int* __restrict__ p, int n) {
  int i = blockIdx.x * 256 + threadIdx.x;
  if (i < n) p[i] = 0;
}

// ---- degree histogram over dst ----
__global__ void hist_kernel(const int* __restrict__ dst, int* __restrict__ deg, int E) {
  int e = blockIdx.x * 256 + threadIdx.x;
  if (e < E) atomicAdd(&deg[dst[e]], 1);
}

__global__ void dinv_kernel(const int* __restrict__ deg, float* __restrict__ dinv, int N) {
  int n = blockIdx.x * 256 + threadIdx.x;
  if (n < N) dinv[n] = rsqrt_acc((float)deg[n] + 1.0f);
}

// ---- two-level exclusive scan of deg -> row_ptr ----
__global__ void scan_a(const int* __restrict__ deg, int* __restrict__ partial,
                       int* __restrict__ blockSums, int N) {
  __shared__ int sums[256];
  int t = threadIdx.x;
  int base = blockIdx.x * 1024 + t * 4;
  int v0 = (base + 0) < N ? deg[base + 0] : 0;
  int v1 = (base + 1) < N ? deg[base + 1] : 0;
  int v2 = (base + 2) < N ? deg[base + 2] : 0;
  int v3 = (base + 3) < N ? deg[base + 3] : 0;
  int l0 = v0, l1 = l0 + v1, l2 = l1 + v2, l3 = l2 + v3;
  sums[t] = l3;
  __syncthreads();
  for (int o = 1; o < 256; o <<= 1) {
    int a = sums[t];
    int b = (t >= o) ? sums[t - o] : 0;
    __syncthreads();
    sums[t] = a + b;
    __syncthreads();
  }
  int excl = sums[t] - l3;
  if (t == 0) blockSums[blockIdx.x] = sums[255];
  if (base + 0 < N) partial[base + 0] = excl;
  if (base + 1 < N) partial[base + 1] = excl + l0;
  if (base + 2 < N) partial[base + 2] = excl + l1;
  if (base + 3 < N) partial[base + 3] = excl + l2;
}

__global__ void scan_b(int* __restrict__ blockSums, int nb) {
  __shared__ int s[256];
  int t = threadIdx.x;
  int orig = (t < nb) ? blockSums[t] : 0;
  s[t] = orig;
  __syncthreads();
  for (int o = 1; o < 256; o <<= 1) {
    int a = s[t];
    int b = (t >= o) ? s[t - o] : 0;
    __syncthreads();
    s[t] = a + b;
    __syncthreads();
  }
  if (t < nb) blockSums[t] = s[t] - orig;
}

__global__ void scan_c(int* __restrict__ row_ptr, const int* __restrict__ blockOff,
                       int* __restrict__ cursor, int N, int E) {
  int n = blockIdx.x * 256 + threadIdx.x;
  if (n < N) {
    int v = row_ptr[n] + blockOff[n >> 10];
    row_ptr[n] = v;
    cursor[n] = v;
  }
  if (n == 0 && blockIdx.x == 0) row_ptr[N] = E;
}

// ---- CSR placement: single int2 record per edge ----
__global__ void place_kernel(const int* __restrict__ src, const int* __restrict__ dst,
                             const float* __restrict__ dinv, int* __restrict__ cursor,
                             int2* __restrict__ ePair, int E) {
  int e = blockIdx.x * 256 + threadIdx.x;
  if (e < E) {
    int s = src[e], d = dst[e];
    int pos = atomicAdd(&cursor[d], 1);
    int2 rec;
    rec.x = s;
    rec.y = __float_as_int(dinv[s] * dinv[d]);
    ePair[pos] = rec;
  }
}

// ---- W1 -> transposed, K-padded fp16 (once per call, tiny) ----
__global__ void convW1_kernel(const float* __restrict__ W1, unsigned short* __restrict__ Wh) {
  int idx = blockIdx.x * 256 + threadIdx.x;   // 128*512
  if (idx >= HID * KPAD) return;
  int n = idx >> 9, k = idx & (KPAD - 1);
  float f = (k < IN_DIM) ? W1[(size_t)k * HID + n] : 0.f;
  Wh[idx] = h16_of(f);
}

// ---- GEMM1 (MFMA): H1[N,128] = X[N,500] @ W1, single fp16 product ----
// Round-6 proven loop skeleton (plain __syncthreads, inline loads); fp16
// operands cut MFMA 12->4 per round, LDS 30->15 KB (8-block wave cap).
// fp16 K=500 accum error ~5e-4 RMS << 0.0156 observed absmax.
#define LSTR 40

__global__ __launch_bounds__(256) void gemm1_kernel(const float* __restrict__ X,
                                                    const unsigned short* __restrict__ Wh,
                                                    unsigned short* __restrict__ H1, int N) {
  __shared__ unsigned short sA[64 * LSTR];
  __shared__ unsigned short sB[128 * LSTR];
  const int t = threadIdx.x;
  const int rowBase = blockIdx.x * 64;
  const int lane = t & 63;
  const int w = t >> 6;
  const int rw = w & 1;          // row half: rows rw*32..+32
  const int cw = w >> 1;         // col half: cols cw*64..+64
  const int m = lane & 31;
  const int quad = lane >> 5;    // k-offset quad*8

  f32x16 acc[2];
  acc[0] = (f32x16)(0.f);
  acc[1] = (f32x16)(0.f);

  // A staging: 64 rows x 32 k, 8 elems/thread
  const int arow = t >> 2;             // 0..63
  const int akoff = (t & 3) * 8;       // 0,8,16,24
  const bool arok = (rowBase + arow) < N;
  const float* xrow = X + (size_t)(rowBase + (arok ? arow : 0)) * IN_DIM;
  // B staging: 128 rows x 32 k, 16 elems/thread
  const int brow = t >> 1;             // 0..127
  const int bkoff = (t & 1) * 16;      // 0 / 16

  for (int k0 = 0; k0 < KPAD; k0 += 32) {
    __syncthreads();   // protect LDS reuse from previous round's readers
    // ---- stage A: fp32 -> fp16, 8 elems ----
    {
      float f[8];
      if (arok && (k0 + akoff + 8) <= IN_DIM) {
        const float4* p = (const float4*)(xrow + k0 + akoff);
        float4 v0 = p[0], v1 = p[1];
        f[0] = v0.x; f[1] = v0.y; f[2] = v0.z; f[3] = v0.w;
        f[4] = v1.x; f[5] = v1.y; f[6] = v1.z; f[7] = v1.w;
      } else {
#pragma unroll
        for (int j = 0; j < 8; j++) {
          int k = k0 + akoff + j;
          f[j] = (arok && k < IN_DIM) ? xrow[k] : 0.f;
        }
      }
      ushort4 h0, h1v;
      h0.x = h16_of(f[0]); h0.y = h16_of(f[1]); h0.z = h16_of(f[2]); h0.w = h16_of(f[3]);
      h1v.x = h16_of(f[4]); h1v.y = h16_of(f[5]); h1v.z = h16_of(f[6]); h1v.w = h16_of(f[7]);
      *(ushort4*)&sA[arow * LSTR + akoff] = h0;
      *(ushort4*)&sA[arow * LSTR + akoff + 4] = h1v;
    }
    // ---- stage B: precomputed fp16 (B^T layout [n][k]) ----
    {
      const size_t gb = (size_t)brow * KPAD + k0 + bkoff;
      uint4 b0 = *(const uint4*)&Wh[gb];
      uint4 b1v = *(const uint4*)&Wh[gb + 8];
      *(uint4*)&sB[brow * LSTR + bkoff] = b0;
      *(uint4*)&sB[brow * LSTR + bkoff + 8] = b1v;
    }
    __syncthreads();

    // ---- compute: 2 k16 substeps x 2 n-tiles x 1 mfma ----
#pragma unroll
    for (int sub = 0; sub < 2; sub++) {
      const int ks = sub * 16 + quad * 8;
      f16x8 av = *(const f16x8*)&sA[(rw * 32 + m) * LSTR + ks];
#pragma unroll
      for (int nt = 0; nt < 2; nt++) {
        f16x8 bv = *(const f16x8*)&sB[(cw * 64 + nt * 32 + m) * LSTR + ks];
        acc[nt] = __builtin_amdgcn_mfma_f32_32x32x16_f16(av, bv, acc[nt], 0, 0, 0);
      }
    }
  }

  // ---- epilogue: C/D layout col=lane&31, row=(reg&3)+8*(reg>>2)+4*quad ----
#pragma unroll
  for (int nt = 0; nt < 2; nt++) {
#pragma unroll
    for (int r = 0; r < 16; r++) {
      int rowin = (r & 3) + 8 * (r >> 2) + 4 * quad;
      int grow = rowBase + rw * 32 + rowin;
      if (grow < N) H1[(size_t)grow * HID + cw * 64 + nt * 32 + m] = h16_of(acc[nt][r]);
    }
  }
}

// ---- agg1: thread per (node, col-group-of-8); fp16 gather (16B/lane) ----
__global__ void agg1_kernel(const unsigned short* __restrict__ h1, const int* __restrict__ row_ptr,
                            const int2* __restrict__ ePair, const float* __restrict__ dinv,
                            const float* __restrict__ b1, unsigned short* __restrict__ hrelu, int N) {
  int gid = blockIdx.x * 256 + threadIdx.x;
  int n = gid >> 4, c8 = (gid & 15) * 8;
  if (n >= N) return;
  float di = dinv[n];
  float sl = di * di;
  float acc[8];
  u16x8 sv = *(const u16x8*)&h1[(size_t)n * HID + c8];
#pragma unroll
  for (int j = 0; j < 8; j++) acc[j] = sl * h16_back(sv[j]);
  int i = row_ptr[n];
  const int s1 = row_ptr[n + 1];
  for (; i + 4 <= s1; i += 4) {
    int2 e0 = ePair[i], e1 = ePair[i + 1], e2 = ePair[i + 2], e3 = ePair[i + 3];
    float w0 = __int_as_float(e0.y), w1 = __int_as_float(e1.y);
    float w2 = __int_as_float(e2.y), w3 = __int_as_float(e3.y);
    u16x8 v0 = *(const u16x8*)&h1[(size_t)e0.x * HID + c8];
    u16x8 v1 = *(const u16x8*)&h1[(size_t)e1.x * HID + c8];
    u16x8 v2 = *(const u16x8*)&h1[(size_t)e2.x * HID + c8];
    u16x8 v3 = *(const u16x8*)&h1[(size_t)e3.x * HID + c8];
#pragma unroll
    for (int j = 0; j < 8; j++) {
      acc[j] += w0 * h16_back(v0[j]) + w1 * h16_back(v1[j]) +
                w2 * h16_back(v2[j]) + w3 * h16_back(v3[j]);
    }
  }
  for (; i < s1; i++) {
    int2 e = ePair[i];
    float w = __int_as_float(e.y);
    u16x8 v = *(const u16x8*)&h1[(size_t)e.x * HID + c8];
#pragma unroll
    for (int j = 0; j < 8; j++) acc[j] += w * h16_back(v[j]);
  }
  u16x8 r;
#pragma unroll
  for (int j = 0; j < 8; j++) {
    float v = fmaxf(acc[j] + b1[c8 + j], 0.f);
    r[j] = h16_of(v);
  }
  *(u16x8*)&hrelu[(size_t)n * HID + c8] = r;
}

// ---- GEMM2: H2[N,40] = hrelu[N,128] @ W2[128,40] (fp16 in, fp16 out) ----
__global__ __launch_bounds__(256) void gemm2_kernel(const unsigned short* __restrict__ A,
                                                    const float* __restrict__ W2,
                                                    unsigned short* __restrict__ H2, int N) {
  __shared__ float tA[64 * 129];
  __shared__ float w2s[128 * 48];
  const int t = threadIdx.x;
  const int rowBase = blockIdx.x * 64;
  for (int idx = t; idx < 128 * 48; idx += 256) {
    int k = idx / 48, c = idx - k * 48;
    w2s[idx] = (c < OUTD) ? W2[k * OUTD + c] : 0.f;
  }
  for (int f = t; f < 1024; f += 256) {
    int row = f >> 4, c8 = (f & 15) * 8;
    u16x8 v = (u16x8)(0);
    if (rowBase + row < N) v = *(const u16x8*)&A[(size_t)(rowBase + row) * HID + c8];
#pragma unroll
    for (int j = 0; j < 8; j++) tA[row * 129 + c8 + j] = h16_back(v[j]);
  }
  __syncthreads();
  const int row = t >> 2;
  const int c0 = (t & 3) * 12;
  float acc[12];
#pragma unroll
  for (int j = 0; j < 12; j++) acc[j] = 0.f;
  for (int k = 0; k < HID; k++) {
    float a = tA[row * 129 + k];
    const float* bp = &w2s[k * 48 + c0];
#pragma unroll
    for (int j = 0; j < 12; j++) acc[j] += a * bp[j];
  }
  int r = rowBase + row;
  if (r < N) {
#pragma unroll
    for (int j = 0; j < 12; j++) {
      int c = c0 + j;
      if (c < OUTD) H2[(size_t)r * OUTD + c] = h16_of(acc[j]);
    }
  }
}

// ---- agg2: thread per (node, col-group-of-4); fp16 gather (8B/lane) ----
__global__ void agg2_kernel(const unsigned short* __restrict__ h2, const int* __restrict__ row_ptr,
                            const int2* __restrict__ ePair, const float* __restrict__ dinv,
                            const float* __restrict__ b2, float* __restrict__ out, int N) {
  int gid = blockIdx.x * 256 + threadIdx.x;
  int n = gid / 10;
  int c4 = (gid - n * 10) * 4;
  if (n >= N) return;
  float di = dinv[n];
  float sl = di * di;
  float acc[4];
  u16x4 sv = *(const u16x4*)&h2[(size_t)n * OUTD + c4];
#pragma unroll
  for (int j = 0; j < 4; j++) acc[j] = sl * h16_back(sv[j]);
  int i = row_ptr[n];
  const int s1 = row_ptr[n + 1];
  for (; i + 4 <= s1; i += 4) {
    int2 e0 = ePair[i], e1 = ePair[i + 1], e2 = ePair[i + 2], e3 = ePair[i + 3];
    float w0 = __int_as_float(e0.y), w1 = __int_as_float(e1.y);
    float w2 = __int_as_float(e2.y), w3 = __int_as_float(e3.y);
    u16x4 v0 = *(const u16x4*)&h2[(size_t)e0.x * OUTD + c4];
    u16x4 v1 = *(const u16x4*)&h2[(size_t)e1.x * OUTD + c4];
    u16x4 v2 = *(const u16x4*)&h2[(size_t)e2.x * OUTD + c4];
    u16x4 v3 = *(const u16x4*)&h2[(size_t)e3.x * OUTD + c4];
#pragma unroll
    for (int j = 0; j < 4; j++) {
      acc[j] += w0 * h16_back(v0[j]) + w1 * h16_back(v1[j]) +
                w2 * h16_back(v2[j]) + w3 * h16_back(v3[j]);
    }
  }
  for (; i < s1; i++) {
    int2 e = ePair[i];
    float w = __int_as_float(e.y);
    u16x4 v = *(const u16x4*)&h2[(size_t)e.x * OUTD + c4];
#pragma unroll
    for (int j = 0; j < 4; j++) acc[j] += w * h16_back(v[j]);
  }
  float* o = &out[(size_t)n * OUTD + c4];
#pragma unroll
  for (int j = 0; j < 4; j++) o[j] = acc[j] + b2[c4 + j];
}

// ---- log_softmax over 40 cols ----
__global__ void lsm_kernel(float* __restrict__ out, int N) {
  int n = blockIdx.x * 256 + threadIdx.x;
  if (n >= N) return;
  float* row = out + (size_t)n * OUTD;
  float v[OUTD];
  float m = -3.4e38f;
#pragma unroll
  for (int j = 0; j < OUTD; j++) {
    v[j] = row[j];
    m = fmaxf(m, v[j]);
  }
  float s = 0.f;
#pragma unroll
  for (int j = 0; j < OUTD; j++) s += expf(v[j] - m);
  float lse = m + logf(s);
#pragma unroll
  for (int j = 0; j < OUTD; j++) row[j] = v[j] - lse;
}

extern "C" void kernel_launch(void* const* d_in, const int* in_sizes, int n_in,
                              void* d_out, int out_size, void* d_ws, size_t ws_size,
                              hipStream_t stream) {
  const float* x  = (const float*)d_in[0];
  const int*   ei = (const int*)d_in[1];
  const float* W1 = (const float*)d_in[2];
  const float* b1 = (const float*)d_in[3];
  const float* W2 = (const float*)d_in[4];
  const float* b2 = (const float*)d_in[5];
  float* out = (float*)d_out;

  const int N = in_sizes[0] / IN_DIM;
  const int E = in_sizes[1] / 2;
  const int* src = ei;
  const int* dst = ei + E;

  char* wsb = (char*)d_ws;
  size_t off = 0;
  auto alloc = [&](size_t bytes) -> char* {
    char* p = wsb + off;
    off = (off + bytes + 1023) & ~(size_t)1023;
    return p;
  };
  int*   deg       = (int*)alloc((size_t)N * 4);
  float* dinv      = (float*)alloc((size_t)N * 4);
  int*   blockSums = (int*)alloc(1024);
  int*   row_ptr   = (int*)alloc((size_t)(N + 1) * 4);
  int*   cursor    = (int*)alloc((size_t)N * 4);
  int2*  ePair     = (int2*)alloc((size_t)E * 8);
  unsigned short* Wh = (unsigned short*)alloc((size_t)HID * KPAD * 2);
  unsigned short* h1h    = (unsigned short*)alloc((size_t)N * HID * 2);
  unsigned short* hreluh = (unsigned short*)alloc((size_t)N * HID * 2);
  unsigned short* h2h    = h1h;  // h1 dead after agg1
  (void)n_in; (void)out_size;

  if (off > ws_size) return;  // visible failure instead of OOB crash

  const int gE = (E + 255) / 256;
  const int gN = (N + 255) / 256;
  const int nb = (N + 1023) / 1024;

  zero_kernel<<<gN, 256, 0, stream>>>(deg, N);
  hist_kernel<<<gE, 256, 0, stream>>>(dst, deg, E);
  dinv_kernel<<<gN, 256, 0, stream>>>(deg, dinv, N);
  scan_a<<<nb, 256, 0, stream>>>(deg, row_ptr, blockSums, N);
  scan_b<<<1, 256, 0, stream>>>(blockSums, nb);
  scan_c<<<gN, 256, 0, stream>>>(row_ptr, blockSums, cursor, N, E);
  place_kernel<<<gE, 256, 0, stream>>>(src, dst, dinv, cursor, ePair, E);
  convW1_kernel<<<(HID * KPAD + 255) / 256, 256, 0, stream>>>(W1, Wh);

  gemm1_kernel<<<(N + 63) / 64, 256, 0, stream>>>(x, Wh, h1h, N);
  agg1_kernel<<<(N * 16 + 255) / 256, 256, 0, stream>>>(h1h, row_ptr, ePair, dinv, b1, hreluh, N);
  gemm2_kernel<<<(N + 63) / 64, 256, 0, stream>>>(hreluh, W2, h2h, N);
  agg2_kernel<<<(N * 10 + 255) / 256, 256, 0, stream>>>(h2h, row_ptr, ePair, dinv, b2, out, N);
  lsm_kernel<<<gN, 256, 0, stream>>>(out, N);
}

// Round 8
// 634.962 us; speedup vs baseline: 1.0124x; 1.0124x over previous
//
#include <hip/hip_runtime.h>
#include <hip/hip_bf16.h>

#define IN_DIM 500
#define HID 128
#define OUTD 40
#define KPAD 512

typedef _Float16 f16x8 __attribute__((ext_vector_type(8)));
typedef float f32x16 __attribute__((ext_vector_type(16)));
typedef unsigned short u16x8 __attribute__((ext_vector_type(8)));
typedef unsigned short u16x4 __attribute__((ext_vector_type(4)));

static __device__ __forceinline__ float rsqrt_acc(float x) {
  float r = rsqrtf(x);
  return r * (1.5f - 0.5f * x * r * r);
}

// fp16 (10 mantissa bits): intermediates h1/hrelu/h2 and gemm1 operands
static __device__ __forceinline__ unsigned short h16_of(float f) {
  _Float16 h = (_Float16)f;
  return __builtin_bit_cast(unsigned short, h);
}
static __device__ __forceinline__ float h16_back(unsigned short u) {
  return (float)__builtin_bit_cast(_Float16, u);
}

// ---- zero-fill (graph-capture-safe) ----
__global__ void zero_kernel(int* __restrict__ p, int n) {
  int i = blockIdx.x * 256 + threadIdx.x;
  if (i < n) p[i] = 0;
}

// ---- degree histogram over dst ----
__global__ void hist_kernel(const int* __restrict__ dst, int* __restrict__ deg, int E) {
  int e = blockIdx.x * 256 + threadIdx.x;
  if (e < E) atomicAdd(&deg[dst[e]], 1);
}

__global__ void dinv_kernel(const int* __restrict__ deg, float* __restrict__ dinv, int N) {
  int n = blockIdx.x * 256 + threadIdx.x;
  if (n < N) dinv[n] = rsqrt_acc((float)deg[n] + 1.0f);
}

// ---- two-level exclusive scan of deg -> row_ptr ----
__global__ void scan_a(const int* __restrict__ deg, int* __restrict__ partial,
                       int* __restrict__ blockSums, int N) {
  __shared__ int sums[256];
  int t = threadIdx.x;
  int base = blockIdx.x * 1024 + t * 4;
  int v0 = (base + 0) < N ? deg[base + 0] : 0;
  int v1 = (base + 1) < N ? deg[base + 1] : 0;
  int v2 = (base + 2) < N ? deg[base + 2] : 0;
  int v3 = (base + 3) < N ? deg[base + 3] : 0;
  int l0 = v0, l1 = l0 + v1, l2 = l1 + v2, l3 = l2 + v3;
  sums[t] = l3;
  __syncthreads();
  for (int o = 1; o < 256; o <<= 1) {
    int a = sums[t];
    int b = (t >= o) ? sums[t - o] : 0;
    __syncthreads();
    sums[t] = a + b;
    __syncthreads();
  }
  int excl = sums[t] - l3;
  if (t == 0) blockSums[blockIdx.x] = sums[255];
  if (base + 0 < N) partial[base + 0] = excl;
  if (base + 1 < N) partial[base + 1] = excl + l0;
  if (base + 2 < N) partial[base + 2] = excl + l1;
  if (base + 3 < N) partial[base + 3] = excl + l2;
}

__global__ void scan_b(int* __restrict__ blockSums, int nb) {
  __shared__ int s[256];
  int t = threadIdx.x;
  int orig = (t < nb) ? blockSums[t] : 0;
  s[t] = orig;
  __syncthreads();
  for (int o = 1; o < 256; o <<= 1) {
    int a = s[t];
    int b = (t >= o) ? s[t - o] : 0;
    __syncthreads();
    s[t] = a + b;
    __syncthreads();
  }
  if (t < nb) blockSums[t] = s[t] - orig;
}

__global__ void scan_c(int* __restrict__ row_ptr, const int* __restrict__ blockOff,
                       int* __restrict__ cursor, int N, int E) {
  int n = blockIdx.x * 256 + threadIdx.x;
  if (n < N) {
    int v = row_ptr[n] + blockOff[n >> 10];
    row_ptr[n] = v;
    cursor[n] = v;
  }
  if (n == 0 && blockIdx.x == 0) row_ptr[N] = E;
}

// ---- CSR placement: single int2 record per edge ----
__global__ void place_kernel(const int* __restrict__ src, const int* __restrict__ dst,
                             const float* __restrict__ dinv, int* __restrict__ cursor,
                             int2* __restrict__ ePair, int E) {
  int e = blockIdx.x * 256 + threadIdx.x;
  if (e < E) {
    int s = src[e], d = dst[e];
    int pos = atomicAdd(&cursor[d], 1);
    int2 rec;
    rec.x = s;
    rec.y = __float_as_int(dinv[s] * dinv[d]);
    ePair[pos] = rec;
  }
}

// ---- W1 -> transposed, K-padded fp16 (once per call, tiny) ----
__global__ void convW1_kernel(const float* __restrict__ W1, unsigned short* __restrict__ Wh) {
  int idx = blockIdx.x * 256 + threadIdx.x;   // 128*512
  if (idx >= HID * KPAD) return;
  int n = idx >> 9, k = idx & (KPAD - 1);
  float f = (k < IN_DIM) ? W1[(size_t)k * HID + n] : 0.f;
  Wh[idx] = h16_of(f);
}

// ---- GEMM1 (MFMA): H1[N,128] = X[N,500] @ W1, single fp16 product ----
// 64x128 tile. BK=128 -> 4 staging rounds (was 16). Rounds proved to be the
// pacing unit (R0/R4/R7 all ~120us at 16 rounds regardless of MFMA count /
// LDS size / tile shape; all pipes <15%). LDS 52KB -> 3 blocks/CU = the 12
// waves/CU the 16-round version already measured. Same k-order => bit-equal.
#define LSTR 136   // 128 + 8 pad: 272B row stride, 16B-aligned reads

__global__ __launch_bounds__(256) void gemm1_kernel(const float* __restrict__ X,
                                                    const unsigned short* __restrict__ Wh,
                                                    unsigned short* __restrict__ H1, int N) {
  __shared__ unsigned short sA[64 * LSTR];
  __shared__ unsigned short sB[128 * LSTR];
  const int t = threadIdx.x;
  const int rowBase = blockIdx.x * 64;
  const int lane = t & 63;
  const int w = t >> 6;
  const int rw = w & 1;          // row half: rows rw*32..+32
  const int cw = w >> 1;         // col half: cols cw*64..+64
  const int m = lane & 31;
  const int quad = lane >> 5;    // k-offset quad*8

  f32x16 acc[2];
  acc[0] = (f32x16)(0.f);
  acc[1] = (f32x16)(0.f);

  // A staging: 64 rows x 128 k, 32 elems/thread
  const int arow = t >> 2;             // 0..63
  const int akoff = (t & 3) * 32;      // 0,32,64,96
  const bool arok = (rowBase + arow) < N;
  const float* xrow = X + (size_t)(rowBase + (arok ? arow : 0)) * IN_DIM;
  // B staging: 128 rows x 128 k, 64 elems/thread
  const int brow = t >> 1;             // 0..127
  const int bkoff = (t & 1) * 64;      // 0 / 64

  for (int k0 = 0; k0 < KPAD; k0 += 128) {   // 4 rounds
    __syncthreads();   // protect LDS reuse from previous round's readers
    // ---- stage A: fp32 -> fp16, 32 elems ----
    if (arok && (k0 + akoff + 32) <= IN_DIM) {
      const float4* p = (const float4*)(xrow + k0 + akoff);
#pragma unroll
      for (int g = 0; g < 4; g++) {
        float4 va = p[2 * g], vb = p[2 * g + 1];
        u16x8 hv;
        hv[0] = h16_of(va.x); hv[1] = h16_of(va.y); hv[2] = h16_of(va.z); hv[3] = h16_of(va.w);
        hv[4] = h16_of(vb.x); hv[5] = h16_of(vb.y); hv[6] = h16_of(vb.z); hv[7] = h16_of(vb.w);
        *(u16x8*)&sA[arow * LSTR + akoff + g * 8] = hv;
      }
    } else {
#pragma unroll
      for (int g = 0; g < 4; g++) {
        u16x8 hv;
#pragma unroll
        for (int j = 0; j < 8; j++) {
          int k = k0 + akoff + g * 8 + j;
          float f = (arok && k < IN_DIM) ? xrow[k] : 0.f;
          hv[j] = h16_of(f);
        }
        *(u16x8*)&sA[arow * LSTR + akoff + g * 8] = hv;
      }
    }
    // ---- stage B: precomputed fp16 (B^T layout [n][k]), 64 elems ----
    {
      const size_t gb = (size_t)brow * KPAD + k0 + bkoff;
#pragma unroll
      for (int g = 0; g < 8; g++) {
        uint4 bv = *(const uint4*)&Wh[gb + g * 8];
        *(uint4*)&sB[brow * LSTR + bkoff + g * 8] = bv;
      }
    }
    __syncthreads();

    // ---- compute: 8 k16 substeps x 2 n-tiles x 1 mfma ----
#pragma unroll
    for (int sub = 0; sub < 8; sub++) {
      const int ks = sub * 16 + quad * 8;
      f16x8 av = *(const f16x8*)&sA[(rw * 32 + m) * LSTR + ks];
#pragma unroll
      for (int nt = 0; nt < 2; nt++) {
        f16x8 bv = *(const f16x8*)&sB[(cw * 64 + nt * 32 + m) * LSTR + ks];
        acc[nt] = __builtin_amdgcn_mfma_f32_32x32x16_f16(av, bv, acc[nt], 0, 0, 0);
      }
    }
  }

  // ---- epilogue: C/D layout col=lane&31, row=(reg&3)+8*(reg>>2)+4*quad ----
#pragma unroll
  for (int nt = 0; nt < 2; nt++) {
#pragma unroll
    for (int r = 0; r < 16; r++) {
      int rowin = (r & 3) + 8 * (r >> 2) + 4 * quad;
      int grow = rowBase + rw * 32 + rowin;
      if (grow < N) H1[(size_t)grow * HID + cw * 64 + nt * 32 + m] = h16_of(acc[nt][r]);
    }
  }
}

// ---- agg1: thread per (node, col-group-of-8); fp16 gather (16B/lane) ----
__global__ void agg1_kernel(const unsigned short* __restrict__ h1, const int* __restrict__ row_ptr,
                            const int2* __restrict__ ePair, const float* __restrict__ dinv,
                            const float* __restrict__ b1, unsigned short* __restrict__ hrelu, int N) {
  int gid = blockIdx.x * 256 + threadIdx.x;
  int n = gid >> 4, c8 = (gid & 15) * 8;
  if (n >= N) return;
  float di = dinv[n];
  float sl = di * di;
  float acc[8];
  u16x8 sv = *(const u16x8*)&h1[(size_t)n * HID + c8];
#pragma unroll
  for (int j = 0; j < 8; j++) acc[j] = sl * h16_back(sv[j]);
  int i = row_ptr[n];
  const int s1 = row_ptr[n + 1];
  for (; i + 4 <= s1; i += 4) {
    int2 e0 = ePair[i], e1 = ePair[i + 1], e2 = ePair[i + 2], e3 = ePair[i + 3];
    float w0 = __int_as_float(e0.y), w1 = __int_as_float(e1.y);
    float w2 = __int_as_float(e2.y), w3 = __int_as_float(e3.y);
    u16x8 v0 = *(const u16x8*)&h1[(size_t)e0.x * HID + c8];
    u16x8 v1 = *(const u16x8*)&h1[(size_t)e1.x * HID + c8];
    u16x8 v2 = *(const u16x8*)&h1[(size_t)e2.x * HID + c8];
    u16x8 v3 = *(const u16x8*)&h1[(size_t)e3.x * HID + c8];
#pragma unroll
    for (int j = 0; j < 8; j++) {
      acc[j] += w0 * h16_back(v0[j]) + w1 * h16_back(v1[j]) +
                w2 * h16_back(v2[j]) + w3 * h16_back(v3[j]);
    }
  }
  for (; i < s1; i++) {
    int2 e = ePair[i];
    float w = __int_as_float(e.y);
    u16x8 v = *(const u16x8*)&h1[(size_t)e.x * HID + c8];
#pragma unroll
    for (int j = 0; j < 8; j++) acc[j] += w * h16_back(v[j]);
  }
  u16x8 r;
#pragma unroll
  for (int j = 0; j < 8; j++) {
    float v = fmaxf(acc[j] + b1[c8 + j], 0.f);
    r[j] = h16_of(v);
  }
  *(u16x8*)&hrelu[(size_t)n * HID + c8] = r;
}

// ---- GEMM2: H2[N,40] = hrelu[N,128] @ W2[128,40] (fp16 in, fp16 out) ----
__global__ __launch_bounds__(256) void gemm2_kernel(const unsigned short* __restrict__ A,
                                                    const float* __restrict__ W2,
                                                    unsigned short* __restrict__ H2, int N) {
  __shared__ float tA[64 * 129];
  __shared__ float w2s[128 * 48];
  const int t = threadIdx.x;
  const int rowBase = blockIdx.x * 64;
  for (int idx = t; idx < 128 * 48; idx += 256) {
    int k = idx / 48, c = idx - k * 48;
    w2s[idx] = (c < OUTD) ? W2[k * OUTD + c] : 0.f;
  }
  for (int f = t; f < 1024; f += 256) {
    int row = f >> 4, c8 = (f & 15) * 8;
    u16x8 v = (u16x8)(0);
    if (rowBase + row < N) v = *(const u16x8*)&A[(size_t)(rowBase + row) * HID + c8];
#pragma unroll
    for (int j = 0; j < 8; j++) tA[row * 129 + c8 + j] = h16_back(v[j]);
  }
  __syncthreads();
  const int row = t >> 2;
  const int c0 = (t & 3) * 12;
  float acc[12];
#pragma unroll
  for (int j = 0; j < 12; j++) acc[j] = 0.f;
  for (int k = 0; k < HID; k++) {
    float a = tA[row * 129 + k];
    const float* bp = &w2s[k * 48 + c0];
#pragma unroll
    for (int j = 0; j < 12; j++) acc[j] += a * bp[j];
  }
  int r = rowBase + row;
  if (r < N) {
#pragma unroll
    for (int j = 0; j < 12; j++) {
      int c = c0 + j;
      if (c < OUTD) H2[(size_t)r * OUTD + c] = h16_of(acc[j]);
    }
  }
}

// ---- agg2: thread per (node, col-group-of-4); fp16 gather (8B/lane) ----
__global__ void agg2_kernel(const unsigned short* __restrict__ h2, const int* __restrict__ row_ptr,
                            const int2* __restrict__ ePair, const float* __restrict__ dinv,
                            const float* __restrict__ b2, float* __restrict__ out, int N) {
  int gid = blockIdx.x * 256 + threadIdx.x;
  int n = gid / 10;
  int c4 = (gid - n * 10) * 4;
  if (n >= N) return;
  float di = dinv[n];
  float sl = di * di;
  float acc[4];
  u16x4 sv = *(const u16x4*)&h2[(size_t)n * OUTD + c4];
#pragma unroll
  for (int j = 0; j < 4; j++) acc[j] = sl * h16_back(sv[j]);
  int i = row_ptr[n];
  const int s1 = row_ptr[n + 1];
  for (; i + 4 <= s1; i += 4) {
    int2 e0 = ePair[i], e1 = ePair[i + 1], e2 = ePair[i + 2], e3 = ePair[i + 3];
    float w0 = __int_as_float(e0.y), w1 = __int_as_float(e1.y);
    float w2 = __int_as_float(e2.y), w3 = __int_as_float(e3.y);
    u16x4 v0 = *(const u16x4*)&h2[(size_t)e0.x * OUTD + c4];
    u16x4 v1 = *(const u16x4*)&h2[(size_t)e1.x * OUTD + c4];
    u16x4 v2 = *(const u16x4*)&h2[(size_t)e2.x * OUTD + c4];
    u16x4 v3 = *(const u16x4*)&h2[(size_t)e3.x * OUTD + c4];
#pragma unroll
    for (int j = 0; j < 4; j++) {
      acc[j] += w0 * h16_back(v0[j]) + w1 * h16_back(v1[j]) +
                w2 * h16_back(v2[j]) + w3 * h16_back(v3[j]);
    }
  }
  for (; i < s1; i++) {
    int2 e = ePair[i];
    float w = __int_as_float(e.y);
    u16x4 v = *(const u16x4*)&h2[(size_t)e.x * OUTD + c4];
#pragma unroll
    for (int j = 0; j < 4; j++) acc[j] += w * h16_back(v[j]);
  }
  float* o = &out[(size_t)n * OUTD + c4];
#pragma unroll
  for (int j = 0; j < 4; j++) o[j] = acc[j] + b2[c4 + j];
}

// ---- log_softmax over 40 cols ----
__global__ void lsm_kernel(float* __restrict__ out, int N) {
  int n = blockIdx.x * 256 + threadIdx.x;
  if (n >= N) return;
  float* row = out + (size_t)n * OUTD;
  float v[OUTD];
  float m = -3.4e38f;
#pragma unroll
  for (int j = 0; j < OUTD; j++) {
    v[j] = row[j];
    m = fmaxf(m, v[j]);
  }
  float s = 0.f;
#pragma unroll
  for (int j = 0; j < OUTD; j++) s += expf(v[j] - m);
  float lse = m + logf(s);
#pragma unroll
  for (int j = 0; j < OUTD; j++) row[j] = v[j] - lse;
}

extern "C" void kernel_launch(void* const* d_in, const int* in_sizes, int n_in,
                              void* d_out, int out_size, void* d_ws, size_t ws_size,
                              hipStream_t stream) {
  const float* x  = (const float*)d_in[0];
  const int*   ei = (const int*)d_in[1];
  const float* W1 = (const float*)d_in[2];
  const float* b1 = (const float*)d_in[3];
  const float* W2 = (const float*)d_in[4];
  const float* b2 = (const float*)d_in[5];
  float* out = (float*)d_out;

  const int N = in_sizes[0] / IN_DIM;
  const int E = in_sizes[1] / 2;
  const int* src = ei;
  const int* dst = ei + E;

  char* wsb = (char*)d_ws;
  size_t off = 0;
  auto alloc = [&](size_t bytes) -> char* {
    char* p = wsb + off;
    off = (off + bytes + 1023) & ~(size_t)1023;
    return p;
  };
  int*   deg       = (int*)alloc((size_t)N * 4);
  float* dinv      = (float*)alloc((size_t)N * 4);
  int*   blockSums = (int*)alloc(1024);
  int*   row_ptr   = (int*)alloc((size_t)(N + 1) * 4);
  int*   cursor    = (int*)alloc((size_t)N * 4);
  int2*  ePair     = (int2*)alloc((size_t)E * 8);
  unsigned short* Wh = (unsigned short*)alloc((size_t)HID * KPAD * 2);
  unsigned short* h1h    = (unsigned short*)alloc((size_t)N * HID * 2);
  unsigned short* hreluh = (unsigned short*)alloc((size_t)N * HID * 2);
  unsigned short* h2h    = h1h;  // h1 dead after agg1
  (void)n_in; (void)out_size;

  if (off > ws_size) return;  // visible failure instead of OOB crash

  const int gE = (E + 255) / 256;
  const int gN = (N + 255) / 256;
  const int nb = (N + 1023) / 1024;

  zero_kernel<<<gN, 256, 0, stream>>>(deg, N);
  hist_kernel<<<gE, 256, 0, stream>>>(dst, deg, E);
  dinv_kernel<<<gN, 256, 0, stream>>>(deg, dinv, N);
  scan_a<<<nb, 256, 0, stream>>>(deg, row_ptr, blockSums, N);
  scan_b<<<1, 256, 0, stream>>>(blockSums, nb);
  scan_c<<<gN, 256, 0, stream>>>(row_ptr, blockSums, cursor, N, E);
  place_kernel<<<gE, 256, 0, stream>>>(src, dst, dinv, cursor, ePair, E);
  convW1_kernel<<<(HID * KPAD + 255) / 256, 256, 0, stream>>>(W1, Wh);

  gemm1_kernel<<<(N + 63) / 64, 256, 0, stream>>>(x, Wh, h1h, N);
  agg1_kernel<<<(N * 16 + 255) / 256, 256, 0, stream>>>(h1h, row_ptr, ePair, dinv, b1, hreluh, N);
  gemm2_kernel<<<(N + 63) / 64, 256, 0, stream>>>(hreluh, W2, h2h, N);
  agg2_kernel<<<(N * 10 + 255) / 256, 256, 0, stream>>>(h2h, row_ptr, ePair, dinv, b2, out, N);
  lsm_kernel<<<gN, 256, 0, stream>>>(out, N);
}